// Round 1
// baseline (43.613 us; speedup 1.0000x reference)
//
#include <hip/hip_runtime.h>
#include <hip/hip_bf16.h>

// BPR loss: per-graph bucketed pairwise logsigmoid sums.
// Block b handles graph b (s_num[b] = L <= 256 tokens), 256 threads.
// Pair (i,j) contributes logsig(lg[i]-lg[j]) to bucket s=lb[i] iff lb[j]<lb[i].

__device__ __forceinline__ float log_sigmoid(float x) {
    // stable: min(x,0) - log(1 + exp(-|x|))
    return fminf(x, 0.0f) - __logf(1.0f + __expf(-fabsf(x)));
}

__global__ __launch_bounds__(256) void bpr_main(const float* __restrict__ logits,
                                                const int* __restrict__ labels,
                                                const int* __restrict__ s_num,
                                                int B, float* __restrict__ acc) {
    const int b = blockIdx.x;
    const int t = threadIdx.x;

    __shared__ float lg[256];
    __shared__ int   lb[256];
    __shared__ float psum[4];
    __shared__ int   cnt[4];
    __shared__ int   wsum[4];

    if (t < 4) { psum[t] = 0.0f; cnt[t] = 0; }

    // ---- exclusive prefix: offset = sum(s_num[0..b)) ----
    int partial = 0;
    for (int i = t; i < b; i += 256) partial += s_num[i];
    #pragma unroll
    for (int off = 32; off > 0; off >>= 1)
        partial += __shfl_down(partial, off, 64);
    if ((t & 63) == 0) wsum[t >> 6] = partial;
    __syncthreads();
    const int offset = wsum[0] + wsum[1] + wsum[2] + wsum[3];
    const int L = s_num[b];          // guaranteed 2..256

    // ---- stage segment into LDS ----
    if (t < L) {
        lg[t] = logits[offset + t];
        lb[t] = labels[offset + t];
    }
    __syncthreads();

    // ---- pair loop: thread t owns pos-index i = t ----
    float a = 0.0f;
    int   si = 0;
    if (t < L) {
        si = lb[t];
        const float xi = lg[t];
        if (si > 0) {
            for (int j = 0; j < L; ++j) {
                // uniform j across lanes -> LDS broadcast reads
                if (lb[j] < si) a += log_sigmoid(xi - lg[j]);
            }
        }
    }
    if (t < L) {
        atomicAdd(&cnt[si], 1);
        if (si > 0) atomicAdd(&psum[si], a);
    }
    __syncthreads();

    // ---- per-graph epilogue ----
    if (t == 0) {
        float lp = 0.0f;
        int   c  = 0;
        int prefix = cnt[0];                 // nneg for s=1
        #pragma unroll
        for (int s = 1; s < 4; ++s) {
            const int npos = cnt[s];
            if (npos > 0 && prefix > 0) {
                lp += psum[s] / ((float)npos * (float)prefix);
                ++c;
            }
            prefix += npos;
        }
        if (L > 1 && c > 0) {
            atomicAdd(&acc[0], lp / (float)c);  // sum of graph_lp
            atomicAdd(&acc[1], 1.0f);           // n_valid
        }
    }
}

__global__ void bpr_final(const float* __restrict__ acc, float* __restrict__ out) {
    out[0] = -(acc[0] / fmaxf(acc[1], 1.0f));
}

extern "C" void kernel_launch(void* const* d_in, const int* in_sizes, int n_in,
                              void* d_out, int out_size, void* d_ws, size_t ws_size,
                              hipStream_t stream) {
    const float* logits = (const float*)d_in[0];
    const int*   labels = (const int*)d_in[1];
    const int*   s_num  = (const int*)d_in[2];
    const int B = in_sizes[2];

    float* acc = (float*)d_ws;
    hipMemsetAsync(acc, 0, 2 * sizeof(float), stream);

    bpr_main<<<B, 256, 0, stream>>>(logits, labels, s_num, B, acc);
    bpr_final<<<1, 1, 0, stream>>>(acc, (float*)d_out);
}

// Round 2
// 39.177 us; speedup vs baseline: 1.1132x; 1.1132x over previous
//
#include <hip/hip_runtime.h>
#include <hip/hip_bf16.h>

// BPR loss: per-graph bucketed pairwise logsigmoid sums.
// Block b handles graph b (s_num[b] = L in [2,256] tokens), 256 threads.
// Pair (i,j) contributes logsig(lg[i]-lg[j]) to bucket s=lb[i] iff lb[j]<lb[i].
// Block writes graph_lp[b] / valid[b] to d_ws (no atomics); kernel 2 reduces.

__device__ __forceinline__ float log_sigmoid(float x) {
    // stable: min(x,0) - log(1 + exp(-|x|))
    return fminf(x, 0.0f) - __logf(1.0f + __expf(-fabsf(x)));
}

__global__ __launch_bounds__(256) void bpr_main(const float* __restrict__ logits,
                                                const int* __restrict__ labels,
                                                const int* __restrict__ s_num,
                                                int B,
                                                float* __restrict__ glp,
                                                float* __restrict__ flg) {
    const int b = blockIdx.x;
    const int t = threadIdx.x;

    __shared__ float lg[256];
    __shared__ int   lb[256];
    __shared__ float psum[4];
    __shared__ int   cnt[4];
    __shared__ int   wsum[4];

    if (t < 4) { psum[t] = 0.0f; cnt[t] = 0; }

    // ---- exclusive prefix: offset = sum(s_num[0..b)) ----
    int partial = 0;
    for (int i = t; i < b; i += 256) partial += s_num[i];
    #pragma unroll
    for (int off = 32; off > 0; off >>= 1)
        partial += __shfl_down(partial, off, 64);
    if ((t & 63) == 0) wsum[t >> 6] = partial;
    __syncthreads();
    const int offset = wsum[0] + wsum[1] + wsum[2] + wsum[3];
    const int L = s_num[b];          // guaranteed 2..256

    // ---- stage segment into LDS ----
    if (t < L) {
        lg[t] = logits[offset + t];
        lb[t] = labels[offset + t];
    }
    __syncthreads();

    // ---- pair loop: thread t owns pos-index i = t ----
    float a = 0.0f;
    int   si = 0;
    if (t < L) {
        si = lb[t];
        const float xi = lg[t];
        if (si > 0) {
            for (int j = 0; j < L; ++j) {
                // uniform j across lanes -> LDS broadcast reads
                if (lb[j] < si) a += log_sigmoid(xi - lg[j]);
            }
        }
    }
    if (t < L) {
        atomicAdd(&cnt[si], 1);                 // LDS-scope, cheap
        if (si > 0) atomicAdd(&psum[si], a);
    }
    __syncthreads();

    // ---- per-graph epilogue: plain writes, no global atomics ----
    if (t == 0) {
        float lp = 0.0f;
        int   c  = 0;
        int prefix = cnt[0];                 // nneg for s=1
        #pragma unroll
        for (int s = 1; s < 4; ++s) {
            const int npos = cnt[s];
            if (npos > 0 && prefix > 0) {
                lp += psum[s] / ((float)npos * (float)prefix);
                ++c;
            }
            prefix += npos;
        }
        const bool gv = (L > 1) && (c > 0);
        glp[b] = gv ? lp / (float)c : 0.0f;
        flg[b] = gv ? 1.0f : 0.0f;
    }
}

__global__ __launch_bounds__(256) void bpr_reduce(const float* __restrict__ glp,
                                                  const float* __restrict__ flg,
                                                  int B, float* __restrict__ out) {
    const int t = threadIdx.x;
    float s = 0.0f, n = 0.0f;
    for (int i = t; i < B; i += 256) { s += glp[i]; n += flg[i]; }
    #pragma unroll
    for (int off = 32; off > 0; off >>= 1) {
        s += __shfl_down(s, off, 64);
        n += __shfl_down(n, off, 64);
    }
    __shared__ float ws[4], wn[4];
    if ((t & 63) == 0) { ws[t >> 6] = s; wn[t >> 6] = n; }
    __syncthreads();
    if (t == 0) {
        const float S = ws[0] + ws[1] + ws[2] + ws[3];
        const float N = wn[0] + wn[1] + wn[2] + wn[3];
        out[0] = -(S / fmaxf(N, 1.0f));
    }
}

extern "C" void kernel_launch(void* const* d_in, const int* in_sizes, int n_in,
                              void* d_out, int out_size, void* d_ws, size_t ws_size,
                              hipStream_t stream) {
    const float* logits = (const float*)d_in[0];
    const int*   labels = (const int*)d_in[1];
    const int*   s_num  = (const int*)d_in[2];
    const int B = in_sizes[2];

    float* glp = (float*)d_ws;        // [B]
    float* flg = glp + B;             // [B]

    bpr_main<<<B, 256, 0, stream>>>(logits, labels, s_num, B, glp, flg);
    bpr_reduce<<<1, 256, 0, stream>>>(glp, flg, B, (float*)d_out);
}

// Round 3
// 27.892 us; speedup vs baseline: 1.5637x; 1.4046x over previous
//
#include <hip/hip_runtime.h>
#include <hip/hip_bf16.h>

// BPR loss: per-graph bucketed pairwise logsigmoid sums.
// Block b handles graph b (s_num[b] = L in [2,256] tokens), 256 threads.
// Pair (i,j) contributes logsig(lg[i]-lg[j]) to bucket s=lb[i] iff lb[j]<lb[i].
// Inner loop is branchless with uniform ds_read_b128 broadcasts (8 j's/iter).

__device__ __forceinline__ float log_sigmoid(float x) {
    // stable: min(x,0) - log(1 + exp(-|x|))
    return fminf(x, 0.0f) - __logf(1.0f + __expf(-fabsf(x)));
}

__global__ __launch_bounds__(256) void bpr_main(const float* __restrict__ logits,
                                                const int* __restrict__ labels,
                                                const int* __restrict__ s_num,
                                                int B,
                                                float* __restrict__ glp,
                                                float* __restrict__ flg) {
    const int b = blockIdx.x;
    const int t = threadIdx.x;

    __shared__ float lg[256];
    __shared__ int   lb[256];
    __shared__ float psum[4];
    __shared__ int   cnt[4];
    __shared__ int   wsum[4];

    if (t < 4) { psum[t] = 0.0f; cnt[t] = 0; }

    // ---- exclusive prefix: offset = sum(s_num[0..b)) ----
    int partial = 0;
    for (int i = t; i < b; i += 256) partial += s_num[i];
    #pragma unroll
    for (int off = 32; off > 0; off >>= 1)
        partial += __shfl_down(partial, off, 64);
    if ((t & 63) == 0) wsum[t >> 6] = partial;
    __syncthreads();
    const int offset = wsum[0] + wsum[1] + wsum[2] + wsum[3];
    const int L = s_num[b];          // guaranteed 2..256

    // ---- stage segment into LDS, sentinel-padded to 256 ----
    // pad: lb=INT_MAX (never < si), lg=0
    lg[t] = (t < L) ? logits[offset + t] : 0.0f;
    lb[t] = (t < L) ? labels[offset + t] : 0x7fffffff;
    __syncthreads();

    // ---- branchless pair loop: thread t owns pos-index i = t ----
    // si=0 for pad/label-0 threads -> predicate (lb[j] < si) always false.
    const int   si = (t < L) ? lb[t] : 0;
    const float xi = lg[t];
    float a = 0.0f;
    for (int j = 0; j < 256; j += 8) {
        const float4 g0 = *reinterpret_cast<const float4*>(&lg[j]);
        const float4 g1 = *reinterpret_cast<const float4*>(&lg[j + 4]);
        const int4   b0 = *reinterpret_cast<const int4*>(&lb[j]);
        const int4   b1 = *reinterpret_cast<const int4*>(&lb[j + 4]);
        a += (b0.x < si) ? log_sigmoid(xi - g0.x) : 0.0f;
        a += (b0.y < si) ? log_sigmoid(xi - g0.y) : 0.0f;
        a += (b0.z < si) ? log_sigmoid(xi - g0.z) : 0.0f;
        a += (b0.w < si) ? log_sigmoid(xi - g0.w) : 0.0f;
        a += (b1.x < si) ? log_sigmoid(xi - g1.x) : 0.0f;
        a += (b1.y < si) ? log_sigmoid(xi - g1.y) : 0.0f;
        a += (b1.z < si) ? log_sigmoid(xi - g1.z) : 0.0f;
        a += (b1.w < si) ? log_sigmoid(xi - g1.w) : 0.0f;
        if (j + 8 >= L) break;       // uniform across block (L same for all)
    }

    if (t < L) {
        atomicAdd(&cnt[si], 1);                 // LDS-scope, cheap
        if (si > 0) atomicAdd(&psum[si], a);
    }
    __syncthreads();

    // ---- per-graph epilogue: plain writes, no global atomics ----
    if (t == 0) {
        float lp = 0.0f;
        int   c  = 0;
        int prefix = cnt[0];                 // nneg for s=1
        #pragma unroll
        for (int s = 1; s < 4; ++s) {
            const int npos = cnt[s];
            if (npos > 0 && prefix > 0) {
                lp += psum[s] / ((float)npos * (float)prefix);
                ++c;
            }
            prefix += npos;
        }
        const bool gv = (L > 1) && (c > 0);
        glp[b] = gv ? lp / (float)c : 0.0f;
        flg[b] = gv ? 1.0f : 0.0f;
    }
}

__global__ __launch_bounds__(256) void bpr_reduce(const float* __restrict__ glp,
                                                  const float* __restrict__ flg,
                                                  int B, float* __restrict__ out) {
    const int t = threadIdx.x;
    float s = 0.0f, n = 0.0f;
    for (int i = t; i < B; i += 256) { s += glp[i]; n += flg[i]; }
    #pragma unroll
    for (int off = 32; off > 0; off >>= 1) {
        s += __shfl_down(s, off, 64);
        n += __shfl_down(n, off, 64);
    }
    __shared__ float ws[4], wn[4];
    if ((t & 63) == 0) { ws[t >> 6] = s; wn[t >> 6] = n; }
    __syncthreads();
    if (t == 0) {
        const float S = ws[0] + ws[1] + ws[2] + ws[3];
        const float N = wn[0] + wn[1] + wn[2] + wn[3];
        out[0] = -(S / fmaxf(N, 1.0f));
    }
}

extern "C" void kernel_launch(void* const* d_in, const int* in_sizes, int n_in,
                              void* d_out, int out_size, void* d_ws, size_t ws_size,
                              hipStream_t stream) {
    const float* logits = (const float*)d_in[0];
    const int*   labels = (const int*)d_in[1];
    const int*   s_num  = (const int*)d_in[2];
    const int B = in_sizes[2];

    float* glp = (float*)d_ws;        // [B]
    float* flg = glp + B;             // [B]

    bpr_main<<<B, 256, 0, stream>>>(logits, labels, s_num, B, glp, flg);
    bpr_reduce<<<1, 256, 0, stream>>>(glp, flg, B, (float*)d_out);
}

// Round 4
// 14.279 us; speedup vs baseline: 3.0543x; 1.9533x over previous
//
#include <hip/hip_runtime.h>
#include <hip/hip_bf16.h>

// BPR loss, counting-sort formulation.
// Block b handles graph b (L = s_num[b] in [2,256]), 256 threads.
// Key identity: logsig(xi - gj) = xi - ln(e^xi + e^gj).
// Sort tokens by label -> selected j's for a row with label s are exactly
// the sorted prefix [0, P[s]).  Per pair: one add + one v_log_f32.
// sum_j logsig = C*xi - ln2 * sum_j log2(Ei + Ej),  C = P[si].

__global__ __launch_bounds__(256) void bpr_main(const float* __restrict__ logits,
                                                const int* __restrict__ labels,
                                                const int* __restrict__ s_num,
                                                int B,
                                                float* __restrict__ glp,
                                                float* __restrict__ flg) {
    const int b = blockIdx.x;
    const int t = threadIdx.x;

    __shared__ __align__(16) float se[256];   // sorted exp(logit), pad = 0
    __shared__ float sx[256];                 // sorted logit
    __shared__ float psum[4];
    __shared__ int   cnt[4];
    __shared__ int   cur[4];
    __shared__ int   wsum[4];

    if (t < 4) { psum[t] = 0.0f; cnt[t] = 0; cur[t] = 0; }
    se[t] = 0.0f;                 // pad so vector tail reads are benign
    sx[t] = 0.0f;

    // ---- exclusive prefix: offset = sum(s_num[0..b)) ----
    int partial = 0;
    for (int i = t; i < b; i += 256) partial += s_num[i];
    #pragma unroll
    for (int off = 32; off > 0; off >>= 1)
        partial += __shfl_down(partial, off, 64);
    if ((t & 63) == 0) wsum[t >> 6] = partial;
    __syncthreads();
    const int offset = wsum[0] + wsum[1] + wsum[2] + wsum[3];
    const int L = s_num[b];          // guaranteed 2..256

    // ---- load + label histogram ----
    float x = 0.0f;
    int   l = 0;
    if (t < L) {
        x = logits[offset + t];
        l = labels[offset + t];
        atomicAdd(&cnt[l], 1);
    }
    __syncthreads();

    const int c0 = cnt[0], c1 = cnt[1], c2 = cnt[2];
    const int P1 = c0, P2 = c0 + c1, P3 = c0 + c1 + c2;   // P[0] = 0

    // ---- counting-sort scatter: se/sx in label order ----
    if (t < L) {
        const int base = (l == 1) ? P1 : (l == 2) ? P2 : (l == 3) ? P3 : 0;
        const int pos  = base + atomicAdd(&cur[l], 1);
        se[pos] = __expf(x);
        sx[pos] = x;
    }
    __syncthreads();

    // ---- per-row pair loop over sorted prefix [0, C) ----
    int si = 0;
    if (t < L) si = (t >= P1) + (t >= P2) + (t >= P3);
    const int C = (si == 1) ? P1 : (si == 2) ? P2 : (si == 3) ? P3 : 0;

    const float xi = sx[t];
    const float Ei = se[t];
    float acc2 = 0.0f;                // sum of log2(Ei + Ej)
    for (int j = 0; j < C; j += 8) {
        const float4 e0 = *reinterpret_cast<const float4*>(&se[j]);
        const float4 e1 = *reinterpret_cast<const float4*>(&se[j + 4]);
        acc2 += (j + 0 < C) ? __log2f(Ei + e0.x) : 0.0f;
        acc2 += (j + 1 < C) ? __log2f(Ei + e0.y) : 0.0f;
        acc2 += (j + 2 < C) ? __log2f(Ei + e0.z) : 0.0f;
        acc2 += (j + 3 < C) ? __log2f(Ei + e0.w) : 0.0f;
        acc2 += (j + 4 < C) ? __log2f(Ei + e1.x) : 0.0f;
        acc2 += (j + 5 < C) ? __log2f(Ei + e1.y) : 0.0f;
        acc2 += (j + 6 < C) ? __log2f(Ei + e1.z) : 0.0f;
        acc2 += (j + 7 < C) ? __log2f(Ei + e1.w) : 0.0f;
    }

    if (si > 0) {
        const float a = (float)C * xi - 0.69314718055994531f * acc2;
        atomicAdd(&psum[si], a);      // LDS-scope
    }
    __syncthreads();

    // ---- per-graph epilogue: plain writes, no global atomics ----
    if (t == 0) {
        const int P[4] = {0, P1, P2, P3};
        float lp = 0.0f;
        int   c  = 0;
        #pragma unroll
        for (int s = 1; s < 4; ++s) {
            const int npos = cnt[s];
            const int nneg = P[s];
            if (npos > 0 && nneg > 0) {
                lp += psum[s] / ((float)npos * (float)nneg);
                ++c;
            }
        }
        const bool gv = (c > 0);      // L >= 2 always
        glp[b] = gv ? lp / (float)c : 0.0f;
        flg[b] = gv ? 1.0f : 0.0f;
    }
}

__global__ __launch_bounds__(256) void bpr_reduce(const float* __restrict__ glp,
                                                  const float* __restrict__ flg,
                                                  int B, float* __restrict__ out) {
    const int t = threadIdx.x;
    float s = 0.0f, n = 0.0f;
    for (int i = t; i < B; i += 256) { s += glp[i]; n += flg[i]; }
    #pragma unroll
    for (int off = 32; off > 0; off >>= 1) {
        s += __shfl_down(s, off, 64);
        n += __shfl_down(n, off, 64);
    }
    __shared__ float ws[4], wn[4];
    if ((t & 63) == 0) { ws[t >> 6] = s; wn[t >> 6] = n; }
    __syncthreads();
    if (t == 0) {
        const float S = ws[0] + ws[1] + ws[2] + ws[3];
        const float N = wn[0] + wn[1] + wn[2] + wn[3];
        out[0] = -(S / fmaxf(N, 1.0f));
    }
}

extern "C" void kernel_launch(void* const* d_in, const int* in_sizes, int n_in,
                              void* d_out, int out_size, void* d_ws, size_t ws_size,
                              hipStream_t stream) {
    const float* logits = (const float*)d_in[0];
    const int*   labels = (const int*)d_in[1];
    const int*   s_num  = (const int*)d_in[2];
    const int B = in_sizes[2];

    float* glp = (float*)d_ws;        // [B]
    float* flg = glp + B;             // [B]

    bpr_main<<<B, 256, 0, stream>>>(logits, labels, s_num, B, glp, flg);
    bpr_reduce<<<1, 256, 0, stream>>>(glp, flg, B, (float*)d_out);
}

// Round 5
// 13.806 us; speedup vs baseline: 3.1591x; 1.0343x over previous
//
#include <hip/hip_runtime.h>
#include <hip/hip_bf16.h>

// BPR loss, counting-sort + sliced-pair formulation.
// Block b handles graph b (L = s_num[b] in [2,256]); 1024 threads.
// Thread t serves sorted row r = t&255 with j-slice sl = t>>8 (4 slices).
// Identity: sum_j logsig(xi-xj) over sorted prefix [0,C)
//         = C*xi - ln2 * sum_j log2(Ei + Ej),   E = exp(logit), C = P[label].
// Sort is ballot-ranked (no LDS-atomic serialization); slices cover
// 8-aligned chunks j = 8*sl + 32k (float4-exact), partial chunk scalar.

__global__ __launch_bounds__(1024) void bpr_main(const float* __restrict__ logits,
                                                 const int* __restrict__ labels,
                                                 const int* __restrict__ s_num,
                                                 int B,
                                                 float* __restrict__ glp,
                                                 float* __restrict__ flg) {
    const int b  = blockIdx.x;
    const int t  = threadIdx.x;
    const int r  = t & 255;          // sorted row this thread serves
    const int sl = t >> 8;           // j-slice 0..3
    const int w  = t >> 6;           // wave id 0..15
    const int lane = t & 63;

    __shared__ __align__(16) float se[256];   // sorted exp(logit)
    __shared__ float sx[256];                 // sorted logit
    __shared__ float psum[4];
    __shared__ int   wcnt[4][4];              // [wave<4][label]
    __shared__ int   wsum[4];

    if (t < 4) psum[t] = 0.0f;

    // ---- exclusive prefix: offset = sum(s_num[0..b)) (first 4 waves) ----
    if (t < 256) {
        int partial = 0;
        for (int i = t; i < b; i += 256) partial += s_num[i];
        #pragma unroll
        for (int off = 32; off > 0; off >>= 1)
            partial += __shfl_down(partial, off, 64);
        if (lane == 0) wsum[w] = partial;
    }
    __syncthreads();
    const int offset = wsum[0] + wsum[1] + wsum[2] + wsum[3];
    const int L = s_num[b];          // guaranteed 2..256

    // ---- load + ballot histogram/rank (rows live in threads t<256) ----
    float x = 0.0f;
    int   l = -1;
    if (t < 256 && t < L) {
        x = logits[offset + t];
        l = labels[offset + t];
    }
    const unsigned long long m0 = __ballot(l == 0);
    const unsigned long long m1 = __ballot(l == 1);
    const unsigned long long m2 = __ballot(l == 2);
    const unsigned long long m3 = __ballot(l == 3);
    if (w < 4 && lane == 0) {
        wcnt[w][0] = __popcll(m0);
        wcnt[w][1] = __popcll(m1);
        wcnt[w][2] = __popcll(m2);
        wcnt[w][3] = __popcll(m3);
    }
    const unsigned long long below = lane ? (~0ull >> (64 - lane)) : 0ull;
    const unsigned long long mymask = (l == 0) ? m0 : (l == 1) ? m1 : (l == 2) ? m2 : m3;
    const int rank = __popcll(mymask & below);
    __syncthreads();

    // ---- label totals + prefixes (all threads, from 16-int LDS table) ----
    int c0 = wcnt[0][0] + wcnt[1][0] + wcnt[2][0] + wcnt[3][0];
    int c1 = wcnt[0][1] + wcnt[1][1] + wcnt[2][1] + wcnt[3][1];
    int c2 = wcnt[0][2] + wcnt[1][2] + wcnt[2][2] + wcnt[3][2];
    int c3 = wcnt[0][3] + wcnt[1][3] + wcnt[2][3] + wcnt[3][3];
    const int P1 = c0, P2 = c0 + c1, P3 = c0 + c1 + c2;

    // ---- scatter into sorted order ----
    if (t < 256 && t < L) {
        int base = (l == 0) ? 0 : (l == 1) ? P1 : (l == 2) ? P2 : P3;
        for (int w2 = 0; w2 < w; ++w2) base += wcnt[w2][l];
        const int pos = base + rank;
        se[pos] = __expf(x);
        sx[pos] = x;
    }
    __syncthreads();

    // ---- sliced pair loop over sorted prefix [0, C) ----
    int si = 0;
    if (r < L) si = (r >= P1) + (r >= P2) + (r >= P3);
    const int C = (si == 1) ? P1 : (si == 2) ? P2 : (si == 3) ? P3 : 0;
    const float xi = sx[r];
    const float Ei = se[r];

    float acc2 = 0.0f;               // sum of log2(Ei + Ej)
    for (int j = 8 * sl; j + 8 <= C; j += 32) {
        const float4 e0 = *reinterpret_cast<const float4*>(&se[j]);
        const float4 e1 = *reinterpret_cast<const float4*>(&se[j + 4]);
        acc2 += __log2f(Ei + e0.x) + __log2f(Ei + e0.y)
              + __log2f(Ei + e0.z) + __log2f(Ei + e0.w)
              + __log2f(Ei + e1.x) + __log2f(Ei + e1.y)
              + __log2f(Ei + e1.z) + __log2f(Ei + e1.w);
    }
    // partial chunk [C&~7, C) handled by its owning slice, scalar
    const int jb = C & ~7;
    if (si > 0 && sl == ((C >> 3) & 3)) {
        for (int j = jb; j < C; ++j) acc2 += __log2f(Ei + se[j]);
    }
    float v = -0.69314718055994531f * acc2;
    if (sl == 0 && si > 0) v += (float)C * xi;

    // ---- per-label combine: masked wave reductions, lane0 atomics ----
    #pragma unroll
    for (int s2 = 1; s2 < 4; ++s2) {
        float val = (si == s2) ? v : 0.0f;
        #pragma unroll
        for (int off = 32; off > 0; off >>= 1)
            val += __shfl_down(val, off, 64);
        if (lane == 0 && val != 0.0f) atomicAdd(&psum[s2], val);
    }
    __syncthreads();

    // ---- per-graph epilogue ----
    if (t == 0) {
        float lp = 0.0f;
        int   cc = 0;
        if (c1 > 0 && P1 > 0) { lp += psum[1] / ((float)c1 * (float)P1); ++cc; }
        if (c2 > 0 && P2 > 0) { lp += psum[2] / ((float)c2 * (float)P2); ++cc; }
        if (c3 > 0 && P3 > 0) { lp += psum[3] / ((float)c3 * (float)P3); ++cc; }
        const bool gv = (cc > 0);    // L >= 2 always
        glp[b] = gv ? lp / (float)cc : 0.0f;
        flg[b] = gv ? 1.0f : 0.0f;
    }
}

__global__ __launch_bounds__(256) void bpr_reduce(const float* __restrict__ glp,
                                                  const float* __restrict__ flg,
                                                  int B, float* __restrict__ out) {
    const int t = threadIdx.x;
    const int lane = t & 63;
    const int w = t >> 6;
    const int n4 = B >> 2;
    float s = 0.0f, n = 0.0f;
    if (t < 128) {
        const float4* g4 = (const float4*)glp;
        for (int i = t; i < n4; i += 128) { float4 v = g4[i]; s += v.x + v.y + v.z + v.w; }
        if (t == 0)   for (int i = n4 << 2; i < B; ++i) s += glp[i];
    } else {
        const float4* f4 = (const float4*)flg;
        for (int i = t - 128; i < n4; i += 128) { float4 v = f4[i]; n += v.x + v.y + v.z + v.w; }
        if (t == 128) for (int i = n4 << 2; i < B; ++i) n += flg[i];
    }
    float val = s + n;               // waves 0-1 carry s, waves 2-3 carry n
    #pragma unroll
    for (int off = 32; off > 0; off >>= 1)
        val += __shfl_down(val, off, 64);
    __shared__ float wred[4];
    if (lane == 0) wred[w] = val;
    __syncthreads();
    if (t == 0) {
        const float S = wred[0] + wred[1];
        const float N = wred[2] + wred[3];
        out[0] = -(S / fmaxf(N, 1.0f));
    }
}

extern "C" void kernel_launch(void* const* d_in, const int* in_sizes, int n_in,
                              void* d_out, int out_size, void* d_ws, size_t ws_size,
                              hipStream_t stream) {
    const float* logits = (const float*)d_in[0];
    const int*   labels = (const int*)d_in[1];
    const int*   s_num  = (const int*)d_in[2];
    const int B = in_sizes[2];

    float* glp = (float*)d_ws;        // [B]
    float* flg = glp + B;             // [B]

    bpr_main<<<B, 1024, 0, stream>>>(logits, labels, s_num, B, glp, flg);
    bpr_reduce<<<1, 256, 0, stream>>>(glp, flg, B, (float*)d_out);
}